// Round 3
// baseline (554.080 us; speedup 1.0000x reference)
//
#include <hip/hip_runtime.h>
#include <hip/hip_bf16.h>
#include <stdint.h>

#define N_NODES 50000
#define N_EDGES 500000
#define R_REL 8
#define HID 128
#define KDIM 1152            // R*HID + HID
#define N8 400000            // N_NODES * R_REL composite buckets
#define MT 64                // node tile per block in fused kernel
#define NBLK 782             // ceil(N_NODES / MT); 782*64 = 50048
#define CH 136               // LDS chunk row stride (128 + 8 pad) in bf16
#define NUM_GRAPHS 64
#define NUM_CLASSES 16

typedef __attribute__((ext_vector_type(8))) short bf16x8;
typedef __attribute__((ext_vector_type(4))) float f32x4;

// ---------- helpers ----------
__device__ __forceinline__ uint16_t f2bf(float f) {
  uint32_t u = __float_as_uint(f);
  u += 0x7FFFu + ((u >> 16) & 1u);   // RNE
  return (uint16_t)(u >> 16);
}
__device__ __forceinline__ uint32_t pack2bf(float a, float b) {
  return (uint32_t)f2bf(a) | ((uint32_t)f2bf(b) << 16);
}

// ---------- edge counting sort by (dst*8 + rel) ----------
__global__ __launch_bounds__(256) void k_hist(const int* __restrict__ ei, const int* __restrict__ et,
                                              int* __restrict__ deg8) {
  int i = blockIdx.x * 256 + threadIdx.x;
  if (i < N_EDGES) atomicAdd(&deg8[ei[N_EDGES + i] * R_REL + et[i]], 1);
}

__global__ __launch_bounds__(256) void k_scan1(const int* __restrict__ deg8, int* __restrict__ offs8,
                                               int* __restrict__ bsum) {
  __shared__ int sh[256];
  int t = threadIdx.x;
  int base = blockIdx.x * 1024 + t * 4;
  int v[4]; int s = 0;
  #pragma unroll
  for (int i = 0; i < 4; ++i) { int idx = base + i; v[i] = (idx < N8) ? deg8[idx] : 0; s += v[i]; }
  sh[t] = s;
  __syncthreads();
  for (int d = 1; d < 256; d <<= 1) {
    int add = (t >= d) ? sh[t - d] : 0;
    __syncthreads();
    sh[t] += add;
    __syncthreads();
  }
  int run = sh[t] - s;
  if (t == 255) bsum[blockIdx.x] = sh[255];
  #pragma unroll
  for (int i = 0; i < 4; ++i) { int idx = base + i; if (idx < N8) offs8[idx] = run; run += v[i]; }
}

// single-block parallel scan of per-block sums (nb <= 512)
__global__ __launch_bounds__(512) void k_scan2(int* __restrict__ bsum, int nb) {
  __shared__ int sh[512];
  int t = threadIdx.x;
  int v = (t < nb) ? bsum[t] : 0;
  sh[t] = v;
  __syncthreads();
  for (int d = 1; d < 512; d <<= 1) {
    int add = (t >= d) ? sh[t - d] : 0;
    __syncthreads();
    sh[t] += add;
    __syncthreads();
  }
  if (t < nb) bsum[t] = sh[t] - v;   // exclusive
}

__global__ __launch_bounds__(256) void k_scan3(int* __restrict__ offs8, int* __restrict__ nxt,
                                               const int* __restrict__ bsum) {
  int i = blockIdx.x * 256 + threadIdx.x;
  if (i < N8) {
    int o = offs8[i] + bsum[i >> 10];
    offs8[i] = o;
    nxt[i] = o;
  }
  if (i == 0) offs8[N8] = N_EDGES;
}

__global__ __launch_bounds__(256) void k_scatter(const int* __restrict__ ei, const int* __restrict__ et,
                                                 int* __restrict__ nxt, uint16_t* __restrict__ esrc) {
  int i = blockIdx.x * 256 + threadIdx.x;
  if (i < N_EDGES) {
    int key = ei[N_EDGES + i] * R_REL + et[i];
    int p = atomicAdd(&nxt[key], 1);
    esrc[p] = (uint16_t)ei[i];   // src < 2^16
  }
}

// ---------- W prep into MFMA B-fragment order ----------
// Wf idx = ((kcg*8 + nt)*4 + quad)*128 + l16*8 + e  <->  Wfull[k][n],
// n = nt*16+l16, k = kcg*32+quad*8+e. Wave B-frag load = base + lane*16B (coalesced).
__global__ __launch_bounds__(256) void k_prepw(const float* __restrict__ W, const float* __restrict__ root,
                                               uint16_t* __restrict__ Wf) {
  int idx = blockIdx.x * 256 + threadIdx.x;
  if (idx >= HID * KDIM) return;
  int e = idx & 7;
  int l16 = (idx >> 3) & 15;
  int quad = (idx >> 7) & 3;
  int nt = (idx >> 9) & 7;
  int kcg = idx >> 12;
  int n = nt * 16 + l16;
  int k = kcg * 32 + quad * 8 + e;
  float v = (k < R_REL * HID) ? W[(size_t)k * HID + n] : root[(size_t)(k - R_REL * HID) * HID + n];
  Wf[idx] = f2bf(v);
}

// ---------- fused aggregate + GEMM + bias + relu ----------
// 64-node tile/block. Chunk r<8: mean over edges of (node, rel=r); chunk 8: root (x itself).
// Each chunk is K-slice [r*128, r*128+128). Double-buffered LDS; one barrier per chunk.
__global__ __launch_bounds__(256) void k_fused(const float* __restrict__ xin,
                                               const uint16_t* __restrict__ esrc,
                                               const int* __restrict__ offs8,
                                               const uint16_t* __restrict__ Wf,
                                               const float* __restrict__ bias,
                                               float* __restrict__ hout) {
  __shared__ uint16_t Abuf[2][MT][CH];   // 34.8 KB
  int t = threadIdx.x, w = t >> 6, L = t & 63;
  int quad = L >> 4, l16 = L & 15;
  int blockM = blockIdx.x * MT;

  f32x4 acc[4][2];
  #pragma unroll
  for (int i = 0; i < 4; ++i) { acc[i][0] = (f32x4){0,0,0,0}; acc[i][1] = (f32x4){0,0,0,0}; }

  auto agg_chunk = [&](int r, int b) {
    #pragma unroll 1
    for (int nd = 0; nd < 16; ++nd) {
      int m = w * 16 + nd;
      int n = blockM + m;
      uint32_t val = 0;
      if (n < N_NODES) {
        if (r < R_REL) {
          int s = offs8[n * R_REL + r], e = offs8[n * R_REL + r + 1];
          float ax = 0.f, ay = 0.f;
          for (int j = s; j < e; ++j) {
            int src = (int)esrc[j];
            float2 v = *(const float2*)(xin + (size_t)src * HID + L * 2);
            ax += v.x; ay += v.y;
          }
          float inv = (e > s) ? 1.f / (float)(e - s) : 0.f;   // mean; empty -> 0
          val = pack2bf(ax * inv, ay * inv);
        } else {
          float2 v = *(const float2*)(xin + (size_t)n * HID + L * 2);
          val = pack2bf(v.x, v.y);
        }
      }
      *(uint32_t*)&Abuf[b][m][L * 2] = val;
    }
  };

  agg_chunk(0, 0);
  __syncthreads();
  for (int r = 0; r < 9; ++r) {
    if (r + 1 < 9) agg_chunk(r + 1, (r + 1) & 1);   // overlaps MFMA(r) via ILP
    int b = r & 1;
    #pragma unroll
    for (int kc = 0; kc < 4; ++kc) {
      int kcg = r * 4 + kc;
      bf16x8 bfr[2];
      #pragma unroll
      for (int jt = 0; jt < 2; ++jt) {
        int nt = w * 2 + jt;
        bfr[jt] = *(const bf16x8*)(Wf + ((size_t)(kcg * 8 + nt) * 4) * 128 + L * 8);
      }
      bf16x8 af[4];
      #pragma unroll
      for (int it = 0; it < 4; ++it)
        af[it] = *(const bf16x8*)&Abuf[b][it * 16 + l16][kc * 32 + quad * 8];
      #pragma unroll
      for (int it = 0; it < 4; ++it)
        #pragma unroll
        for (int jt = 0; jt < 2; ++jt)
          acc[it][jt] = __builtin_amdgcn_mfma_f32_16x16x32_bf16(af[it], bfr[jt], acc[it][jt], 0, 0, 0);
    }
    __syncthreads();
  }

  // epilogue: C/D layout col=lane&15, row=quad*4+reg
  #pragma unroll
  for (int it = 0; it < 4; ++it) {
    #pragma unroll
    for (int jt = 0; jt < 2; ++jt) {
      int c = (w * 2 + jt) * 16 + l16;
      float bb = bias[c];
      #pragma unroll
      for (int rg = 0; rg < 4; ++rg) {
        int row = blockM + it * 16 + quad * 4 + rg;
        if (row < N_NODES)
          hout[(size_t)row * HID + c] = fmaxf(acc[it][jt][rg] + bb, 0.f);
      }
    }
  }
}

// ---------- graph boundaries (batch sorted) — no atomics ----------
__global__ __launch_bounds__(256) void k_bounds(const int* __restrict__ batch,
                                                int* __restrict__ gs, int* __restrict__ ge) {
  int i = blockIdx.x * 256 + threadIdx.x;
  if (i >= N_NODES) return;
  int b = batch[i];
  if (i == 0) gs[b] = 0;
  else { int pb = batch[i - 1]; if (pb != b) { ge[pb] = i; gs[b] = i; } }
  if (i == N_NODES - 1) ge[b] = N_NODES;
}

// ---------- pooled mean + classifier, one block per graph ----------
__global__ __launch_bounds__(512) void k_poolcls(const float* __restrict__ h,
                                                 const int* __restrict__ gs, const int* __restrict__ ge,
                                                 const float* __restrict__ linW, const float* __restrict__ linb,
                                                 float* __restrict__ out) {
  __shared__ float red[4][HID];
  __shared__ float pooled[HID];
  int g = blockIdx.x;
  int c = threadIdx.x & 127, ph = threadIdx.x >> 7;
  int s = gs[g], e = ge[g];
  float acc = 0.f;
  for (int n = s + ph; n < e; n += 4) acc += h[(size_t)n * HID + c];
  red[ph][c] = acc;
  __syncthreads();
  if (ph == 0) {
    float cnt = fmaxf((float)(e - s), 1.f);
    pooled[c] = (red[0][c] + red[1][c] + red[2][c] + red[3][c]) / cnt;
  }
  __syncthreads();
  if (threadIdx.x < NUM_CLASSES) {
    int cls = threadIdx.x;
    float sv = 0.f;
    #pragma unroll 8
    for (int k = 0; k < HID; ++k) sv += pooled[k] * linW[k * NUM_CLASSES + cls];
    out[g * NUM_CLASSES + cls] = sv + linb[cls];
  }
}

// ---------- launch ----------
extern "C" void kernel_launch(void* const* d_in, const int* in_sizes, int n_in,
                              void* d_out, int out_size, void* d_ws, size_t ws_size,
                              hipStream_t stream) {
  const float* x     = (const float*)d_in[0];
  const int*   ei    = (const int*)d_in[1];   // [2,E]: [0..E) src, [E..2E) dst
  const int*   et    = (const int*)d_in[2];
  const int*   batch = (const int*)d_in[3];
  const float* W1    = (const float*)d_in[4];
  const float* root1 = (const float*)d_in[5];
  const float* b1    = (const float*)d_in[6];
  const float* W2    = (const float*)d_in[7];
  const float* root2 = (const float*)d_in[8];
  const float* b2    = (const float*)d_in[9];
  const float* linW  = (const float*)d_in[10];
  const float* linb  = (const float*)d_in[11];
  float* out = (float*)d_out;

  char* ws = (char*)d_ws;
  size_t off = 0;
  auto alloc = [&](size_t bytes) -> char* {
    char* p = ws + off;
    off += (bytes + 255) & ~(size_t)255;
    return p;
  };
  int*      deg8  = (int*)alloc((size_t)N8 * 4);
  int*      offs8 = (int*)alloc((size_t)(N8 + 1) * 4);
  int*      nxt   = (int*)alloc((size_t)N8 * 4);
  int*      bsum  = (int*)alloc(512 * 4);
  uint16_t* esrc  = (uint16_t*)alloc((size_t)N_EDGES * 2);
  uint16_t* Wf1   = (uint16_t*)alloc((size_t)HID * KDIM * 2);
  uint16_t* Wf2   = (uint16_t*)alloc((size_t)HID * KDIM * 2);
  float*    h1    = (float*)alloc((size_t)N_NODES * HID * 4);
  float*    h2    = (float*)alloc((size_t)N_NODES * HID * 4);
  int*      gb    = (int*)alloc(2 * NUM_GRAPHS * 4);
  int*      gs    = gb;
  int*      ge    = gb + NUM_GRAPHS;

  hipMemsetAsync(deg8, 0, (size_t)N8 * 4, stream);
  hipMemsetAsync(gb, 0, 2 * NUM_GRAPHS * 4, stream);

  int eblocks = (N_EDGES + 255) / 256;
  int nb = (N8 + 1023) / 1024;          // 391 <= 512
  k_hist<<<eblocks, 256, 0, stream>>>(ei, et, deg8);
  k_scan1<<<nb, 256, 0, stream>>>(deg8, offs8, bsum);
  k_scan2<<<1, 512, 0, stream>>>(bsum, nb);
  k_scan3<<<(N8 + 255) / 256, 256, 0, stream>>>(offs8, nxt, bsum);
  k_scatter<<<eblocks, 256, 0, stream>>>(ei, et, nxt, esrc);

  int wblocks = (HID * KDIM + 255) / 256;
  k_prepw<<<wblocks, 256, 0, stream>>>(W1, root1, Wf1);
  k_prepw<<<wblocks, 256, 0, stream>>>(W2, root2, Wf2);

  k_fused<<<NBLK, 256, 0, stream>>>(x,  esrc, offs8, Wf1, b1, h1);
  k_fused<<<NBLK, 256, 0, stream>>>(h1, esrc, offs8, Wf2, b2, h2);   // separate out buffer: gather reads h1 everywhere

  k_bounds<<<(N_NODES + 255) / 256, 256, 0, stream>>>(batch, gs, ge);
  k_poolcls<<<NUM_GRAPHS, 512, 0, stream>>>(h2, gs, ge, linW, linb, out);
}

// Round 4
// 387.477 us; speedup vs baseline: 1.4300x; 1.4300x over previous
//
#include <hip/hip_runtime.h>
#include <hip/hip_bf16.h>
#include <stdint.h>

#define N_NODES 50000
#define N_EDGES 500000
#define R_REL 8
#define HID 128
#define KDIM 1152            // R*HID + HID
#define N8 400000            // N_NODES * R_REL composite buckets
#define MT 64                // node tile per block in fused kernel
#define NBLK 782             // ceil(N_NODES / MT)
#define CH 136               // Abuf row stride in bf16 (272 B, 16-aligned for ds_read_b128)
#define EC 1536              // LDS edge cache capacity (tile avg ~640, sd ~25)
#define NUM_GRAPHS 64
#define NUM_CLASSES 16

typedef __attribute__((ext_vector_type(8))) short bf16x8;
typedef __attribute__((ext_vector_type(4))) float f32x4;

// ---------- helpers ----------
__device__ __forceinline__ uint16_t f2bf(float f) {
  uint32_t u = __float_as_uint(f);
  u += 0x7FFFu + ((u >> 16) & 1u);   // RNE
  return (uint16_t)(u >> 16);
}
__device__ __forceinline__ float bf2f(uint16_t b) {
  return __uint_as_float((uint32_t)b << 16);
}

// ---------- x -> bf16 table ----------
__global__ __launch_bounds__(256) void k_cvt(const float* __restrict__ x, uint16_t* __restrict__ xb) {
  int i = blockIdx.x * 256 + threadIdx.x;          // one float4 -> 4 bf16
  if (i * 4 >= N_NODES * HID) return;
  float4 v = *(const float4*)(x + (size_t)i * 4);
  uint16_t o[4] = {f2bf(v.x), f2bf(v.y), f2bf(v.z), f2bf(v.w)};
  *(uint2*)(xb + (size_t)i * 4) = *(uint2*)o;
}

// ---------- edge counting sort by (dst*8 + rel) ----------
__global__ __launch_bounds__(256) void k_hist(const int* __restrict__ ei, const int* __restrict__ et,
                                              int* __restrict__ deg8) {
  int i = blockIdx.x * 256 + threadIdx.x;
  if (i < N_EDGES) atomicAdd(&deg8[ei[N_EDGES + i] * R_REL + et[i]], 1);
}

__global__ __launch_bounds__(256) void k_scan1(const int* __restrict__ deg8, int* __restrict__ offs8,
                                               int* __restrict__ bsum) {
  __shared__ int sh[256];
  int t = threadIdx.x;
  int base = blockIdx.x * 1024 + t * 4;
  int v[4]; int s = 0;
  #pragma unroll
  for (int i = 0; i < 4; ++i) { int idx = base + i; v[i] = (idx < N8) ? deg8[idx] : 0; s += v[i]; }
  sh[t] = s;
  __syncthreads();
  for (int d = 1; d < 256; d <<= 1) {
    int add = (t >= d) ? sh[t - d] : 0;
    __syncthreads();
    sh[t] += add;
    __syncthreads();
  }
  int run = sh[t] - s;
  if (t == 255) bsum[blockIdx.x] = sh[255];
  #pragma unroll
  for (int i = 0; i < 4; ++i) { int idx = base + i; if (idx < N8) offs8[idx] = run; run += v[i]; }
}

__global__ __launch_bounds__(512) void k_scan2(int* __restrict__ bsum, int nb) {
  __shared__ int sh[512];
  int t = threadIdx.x;
  int v = (t < nb) ? bsum[t] : 0;
  sh[t] = v;
  __syncthreads();
  for (int d = 1; d < 512; d <<= 1) {
    int add = (t >= d) ? sh[t - d] : 0;
    __syncthreads();
    sh[t] += add;
    __syncthreads();
  }
  if (t < nb) bsum[t] = sh[t] - v;   // exclusive
}

__global__ __launch_bounds__(256) void k_scan3(int* __restrict__ offs8, int* __restrict__ nxt,
                                               const int* __restrict__ bsum) {
  int i = blockIdx.x * 256 + threadIdx.x;
  if (i < N8) {
    int o = offs8[i] + bsum[i >> 10];
    offs8[i] = o;
    nxt[i] = o;
  }
  if (i == 0) offs8[N8] = N_EDGES;
}

__global__ __launch_bounds__(256) void k_scatter(const int* __restrict__ ei, const int* __restrict__ et,
                                                 int* __restrict__ nxt, uint16_t* __restrict__ esrc) {
  int i = blockIdx.x * 256 + threadIdx.x;
  if (i < N_EDGES) {
    int key = ei[N_EDGES + i] * R_REL + et[i];
    int p = atomicAdd(&nxt[key], 1);
    esrc[p] = (uint16_t)ei[i];   // src < 2^16
  }
}

// ---------- W prep into MFMA B-fragment order ----------
// Wf idx = ((kcg*8 + nt)*4 + quad)*128 + l16*8 + e  <->  Wfull[k][n],
// n = nt*16+l16, k = kcg*32+quad*8+e. Wave B-frag load = base + lane*16B (coalesced).
__global__ __launch_bounds__(256) void k_prepw(const float* __restrict__ W, const float* __restrict__ root,
                                               uint16_t* __restrict__ Wf) {
  int idx = blockIdx.x * 256 + threadIdx.x;
  if (idx >= HID * KDIM) return;
  int e = idx & 7;
  int l16 = (idx >> 3) & 15;
  int quad = (idx >> 7) & 3;
  int nt = (idx >> 9) & 7;
  int kcg = idx >> 12;
  int n = nt * 16 + l16;
  int k = kcg * 32 + quad * 8 + e;
  float v = (k < R_REL * HID) ? W[(size_t)k * HID + n] : root[(size_t)(k - R_REL * HID) * HID + n];
  Wf[idx] = f2bf(v);
}

// ---------- fused aggregate + GEMM + bias + relu ----------
// 64-node tile. Edge lists + offsets LDS-resident (contiguous under (dst,rel) sort).
// Chunk r<8: mean over (node, rel=r) edges; chunk 8: node's own row (root term).
// Half-wave gathers: lane L -> node pair-half L>>5, features 4*(L&31)..+3.
template<bool OUT_BF16>
__global__ __launch_bounds__(256) void k_fused(const uint16_t* __restrict__ xb,
                                               const uint16_t* __restrict__ esrc,
                                               const int* __restrict__ offs8,
                                               const uint16_t* __restrict__ Wf,
                                               const float* __restrict__ bias,
                                               void* __restrict__ hout) {
  __shared__ uint16_t Abuf[2][MT][CH];   // 34816 B
  __shared__ uint16_t sedge[EC];         // 3072 B
  __shared__ int soffs[MT * R_REL + 8];  // 2080 B  -> total ~40 KB -> 4 blocks/CU
  int t = threadIdx.x, w = t >> 6, L = t & 63;
  int quad = L >> 4, l16 = L & 15;
  int hf = L >> 5, j = L & 31;           // half-wave node select, feature quad
  int blockM = blockIdx.x * MT;
  int tileN = min(MT, N_NODES - blockM);

  int ebase = offs8[blockM * R_REL];
  int eend  = offs8[(blockM + tileN) * R_REL];
  int ecnt  = eend - ebase;
  bool cached = (ecnt <= EC);
  int S = tileN * R_REL + 1;
  for (int i = t; i < S; i += 256) soffs[i] = offs8[blockM * R_REL + i] - ebase;
  if (cached)
    for (int i = t; i < ecnt; i += 256) sedge[i] = esrc[ebase + i];

  f32x4 acc[4][2];
  #pragma unroll
  for (int i = 0; i < 4; ++i) { acc[i][0] = (f32x4){0,0,0,0}; acc[i][1] = (f32x4){0,0,0,0}; }

  // aggregate one chunk into Abuf[b]; 8 node-pairs per wave, 2 nodes in flight per pair
  auto agg_chunk = [&](int r, int b) {
    #pragma unroll 2
    for (int p = 0; p < 8; ++p) {
      int m = p * 8 + w * 2 + hf;        // interleaved node assignment balances degree
      int n = blockM + m;
      uint2 val = {0u, 0u};
      if (n < N_NODES) {
        float4 a = {0.f, 0.f, 0.f, 0.f};
        if (r < R_REL) {
          int s = soffs[m * R_REL + r], e = soffs[m * R_REL + r + 1];
          for (int k = s; k < e; ++k) {
            int src = cached ? (int)sedge[k] : (int)esrc[ebase + k];
            ushort4 v = *(const ushort4*)(xb + (size_t)src * HID + j * 4);
            a.x += bf2f(v.x); a.y += bf2f(v.y); a.z += bf2f(v.z); a.w += bf2f(v.w);
          }
          float inv = (e > s) ? 1.f / (float)(e - s) : 0.f;
          a.x *= inv; a.y *= inv; a.z *= inv; a.w *= inv;
        } else {
          ushort4 v = *(const ushort4*)(xb + (size_t)n * HID + j * 4);
          a.x = bf2f(v.x); a.y = bf2f(v.y); a.z = bf2f(v.z); a.w = bf2f(v.w);
        }
        uint16_t o[4] = {f2bf(a.x), f2bf(a.y), f2bf(a.z), f2bf(a.w)};
        val = *(uint2*)o;
      }
      *(uint2*)&Abuf[b][m][j * 4] = val;
    }
  };

  __syncthreads();          // edge cache + offsets ready
  agg_chunk(0, 0);
  __syncthreads();
  for (int r = 0; r < 9; ++r) {
    if (r + 1 < 9) agg_chunk(r + 1, (r + 1) & 1);   // gathers overlap MFMA(r)
    int b = r & 1;
    #pragma unroll
    for (int kc = 0; kc < 4; ++kc) {
      int kcg = r * 4 + kc;
      bf16x8 bfr[2];
      #pragma unroll
      for (int jt = 0; jt < 2; ++jt) {
        int nt = w * 2 + jt;
        bfr[jt] = *(const bf16x8*)(Wf + ((size_t)(kcg * 8 + nt) * 4) * 128 + L * 8);
      }
      bf16x8 af[4];
      #pragma unroll
      for (int it = 0; it < 4; ++it)
        af[it] = *(const bf16x8*)&Abuf[b][it * 16 + l16][kc * 32 + quad * 8];
      #pragma unroll
      for (int it = 0; it < 4; ++it)
        #pragma unroll
        for (int jt = 0; jt < 2; ++jt)
          acc[it][jt] = __builtin_amdgcn_mfma_f32_16x16x32_bf16(af[it], bfr[jt], acc[it][jt], 0, 0, 0);
    }
    __syncthreads();
  }

  // epilogue: C/D layout col=lane&15, row=quad*4+reg
  #pragma unroll
  for (int it = 0; it < 4; ++it) {
    #pragma unroll
    for (int jt = 0; jt < 2; ++jt) {
      int c = (w * 2 + jt) * 16 + l16;
      float bb = bias[c];
      #pragma unroll
      for (int rg = 0; rg < 4; ++rg) {
        int row = blockM + it * 16 + quad * 4 + rg;
        if (row < N_NODES) {
          float o = fmaxf(acc[it][jt][rg] + bb, 0.f);
          if (OUT_BF16) ((uint16_t*)hout)[(size_t)row * HID + c] = f2bf(o);
          else          ((float*)hout)[(size_t)row * HID + c] = o;
        }
      }
    }
  }
}

// ---------- graph boundaries (batch sorted) — no atomics ----------
__global__ __launch_bounds__(256) void k_bounds(const int* __restrict__ batch,
                                                int* __restrict__ gs, int* __restrict__ ge) {
  int i = blockIdx.x * 256 + threadIdx.x;
  if (i >= N_NODES) return;
  int b = batch[i];
  if (i == 0) gs[b] = 0;
  else { int pb = batch[i - 1]; if (pb != b) { ge[pb] = i; gs[b] = i; } }
  if (i == N_NODES - 1) ge[b] = N_NODES;
}

// ---------- pooled mean + classifier, one block per graph ----------
__global__ __launch_bounds__(512) void k_poolcls(const float* __restrict__ h,
                                                 const int* __restrict__ gs, const int* __restrict__ ge,
                                                 const float* __restrict__ linW, const float* __restrict__ linb,
                                                 float* __restrict__ out) {
  __shared__ float red[4][HID];
  __shared__ float pooled[HID];
  int g = blockIdx.x;
  int c = threadIdx.x & 127, ph = threadIdx.x >> 7;
  int s = gs[g], e = ge[g];
  float acc = 0.f;
  for (int n = s + ph; n < e; n += 4) acc += h[(size_t)n * HID + c];
  red[ph][c] = acc;
  __syncthreads();
  if (ph == 0) {
    float cnt = fmaxf((float)(e - s), 1.f);
    pooled[c] = (red[0][c] + red[1][c] + red[2][c] + red[3][c]) / cnt;
  }
  __syncthreads();
  if (threadIdx.x < NUM_CLASSES) {
    int cls = threadIdx.x;
    float sv = 0.f;
    #pragma unroll 8
    for (int k = 0; k < HID; ++k) sv += pooled[k] * linW[k * NUM_CLASSES + cls];
    out[g * NUM_CLASSES + cls] = sv + linb[cls];
  }
}

// ---------- launch ----------
extern "C" void kernel_launch(void* const* d_in, const int* in_sizes, int n_in,
                              void* d_out, int out_size, void* d_ws, size_t ws_size,
                              hipStream_t stream) {
  const float* x     = (const float*)d_in[0];
  const int*   ei    = (const int*)d_in[1];   // [2,E]: [0..E) src, [E..2E) dst
  const int*   et    = (const int*)d_in[2];
  const int*   batch = (const int*)d_in[3];
  const float* W1    = (const float*)d_in[4];
  const float* root1 = (const float*)d_in[5];
  const float* b1    = (const float*)d_in[6];
  const float* W2    = (const float*)d_in[7];
  const float* root2 = (const float*)d_in[8];
  const float* b2    = (const float*)d_in[9];
  const float* linW  = (const float*)d_in[10];
  const float* linb  = (const float*)d_in[11];
  float* out = (float*)d_out;

  char* ws = (char*)d_ws;
  size_t off = 0;
  auto alloc = [&](size_t bytes) -> char* {
    char* p = ws + off;
    off += (bytes + 255) & ~(size_t)255;
    return p;
  };
  int*      deg8  = (int*)alloc((size_t)N8 * 4);
  int*      offs8 = (int*)alloc((size_t)(N8 + 1) * 4);
  int*      nxt   = (int*)alloc((size_t)N8 * 4);
  int*      bsum  = (int*)alloc(512 * 4);
  uint16_t* esrc  = (uint16_t*)alloc((size_t)N_EDGES * 2);
  uint16_t* xb    = (uint16_t*)alloc((size_t)N_NODES * HID * 2);
  uint16_t* Wf1   = (uint16_t*)alloc((size_t)HID * KDIM * 2);
  uint16_t* Wf2   = (uint16_t*)alloc((size_t)HID * KDIM * 2);
  uint16_t* h1b   = (uint16_t*)alloc((size_t)N_NODES * HID * 2);
  float*    h2    = (float*)alloc((size_t)N_NODES * HID * 4);
  int*      gb    = (int*)alloc(2 * NUM_GRAPHS * 4);
  int*      gs    = gb;
  int*      ge    = gb + NUM_GRAPHS;

  hipMemsetAsync(deg8, 0, (size_t)N8 * 4, stream);
  hipMemsetAsync(gb, 0, 2 * NUM_GRAPHS * 4, stream);

  int eblocks = (N_EDGES + 255) / 256;
  int nb = (N8 + 1023) / 1024;          // 391 <= 512
  k_cvt<<<(N_NODES * HID / 4 + 255) / 256, 256, 0, stream>>>(x, xb);
  k_hist<<<eblocks, 256, 0, stream>>>(ei, et, deg8);
  k_scan1<<<nb, 256, 0, stream>>>(deg8, offs8, bsum);
  k_scan2<<<1, 512, 0, stream>>>(bsum, nb);
  k_scan3<<<(N8 + 255) / 256, 256, 0, stream>>>(offs8, nxt, bsum);
  k_scatter<<<eblocks, 256, 0, stream>>>(ei, et, nxt, esrc);

  int wblocks = (HID * KDIM + 255) / 256;
  k_prepw<<<wblocks, 256, 0, stream>>>(W1, root1, Wf1);
  k_prepw<<<wblocks, 256, 0, stream>>>(W2, root2, Wf2);

  k_fused<true ><<<NBLK, 256, 0, stream>>>(xb,  esrc, offs8, Wf1, b1, h1b);
  k_fused<false><<<NBLK, 256, 0, stream>>>(h1b, esrc, offs8, Wf2, b2, h2);

  k_bounds<<<(N_NODES + 255) / 256, 256, 0, stream>>>(batch, gs, ge);
  k_poolcls<<<NUM_GRAPHS, 512, 0, stream>>>(h2, gs, ge, linW, linb, out);
}